// Round 3
// baseline (349.708 us; speedup 1.0000x reference)
//
#include <hip/hip_runtime.h>
#include <hip/hip_bf16.h>
#include <stdint.h>

#define D_DIM 512
#define B_CTX 512
#define M_MEM 65536
#define BM 128
#define BB 128
#define BK 32
#define LDSPAD 40   // 80 B row pitch: 16B-aligned, frag reads 2-way conflict (free)

typedef __attribute__((ext_vector_type(8))) short short8;   // 8 x bf16 bits (4 VGPR)
typedef __attribute__((ext_vector_type(4))) float floatx4;  // MFMA accumulator

__device__ __forceinline__ uint32_t f32_order(float s) {
    uint32_t u = __float_as_uint(s);
    return (u & 0x80000000u) ? ~u : (u | 0x80000000u);
}

// x = hi + lo (hi,lo bf16, both RTN): representation error ~2^-17 relative
__device__ __forceinline__ void split_bf16(float x, uint16_t& h, uint16_t& l) {
    uint32_t uh = (__float_as_uint(x) + 0x8000u) & 0xFFFF0000u;
    float hf = __uint_as_float(uh);
    float lo = x - hf;                       // exact (Sterbenz: hf within 2x of x)
    h = (uint16_t)(uh >> 16);
    l = (uint16_t)((__float_as_uint(lo) + 0x8000u) >> 16);
}

// ---------------- kernel 0: dtype probe + g_best init ----------------
// bf16 data: low-16 halves are sane bf16 exponents (~100% in [96,144]).
// fp32 data: low-16 halves are mantissa bits (~19% "sane").
__global__ void detect_init(const uint32_t* __restrict__ mem_raw,
                            unsigned long long* __restrict__ g_best,
                            uint32_t* __restrict__ flag) {
    __shared__ int cnt;
    if (threadIdx.x == 0) cnt = 0;
    __syncthreads();
    int s = 0;
    #pragma unroll
    for (int i = 0; i < 8; ++i) {
        uint32_t u = mem_raw[threadIdx.x * 8 + i];
        uint32_t e = (u >> 7) & 0xFFu;
        s += (e >= 96u && e <= 144u) ? 1 : 0;
    }
    atomicAdd(&cnt, s);
    #pragma unroll
    for (int i = 0; i < 8; ++i) g_best[threadIdx.x * 8 + i] = 0ull;
    __syncthreads();
    if (threadIdx.x == 0) *flag = (cnt > 256) ? 1u : 0u;   // 1 == bf16 inputs
}

// ---------------- kernel 1: per-row memory inverse norms ----------------
__global__ __launch_bounds__(256) void norm_kernel(const void* __restrict__ memv,
                                                   const uint32_t* __restrict__ flag,
                                                   float* __restrict__ inv_norm) {
    const int wave = threadIdx.x >> 6;
    const int lane = threadIdx.x & 63;
    const int row = blockIdx.x * 4 + wave;
    float s = 0.f;
    if (*flag) {
        const uint4* p = (const uint4*)((const uint16_t*)memv + (size_t)row * D_DIM);
        uint4 v = p[lane];
        uint32_t w[4] = {v.x, v.y, v.z, v.w};
        #pragma unroll
        for (int i = 0; i < 4; ++i) {
            float a = __uint_as_float(w[i] << 16);
            float b = __uint_as_float(w[i] & 0xFFFF0000u);
            s = fmaf(a, a, s);
            s = fmaf(b, b, s);
        }
    } else {
        const float4* p = (const float4*)((const float*)memv + (size_t)row * D_DIM);
        float4 v0 = p[lane];
        float4 v1 = p[lane + 64];
        s = fmaf(v0.x, v0.x, fmaf(v0.y, v0.y, fmaf(v0.z, v0.z, v0.w * v0.w)));
        s = fmaf(v1.x, v1.x, fmaf(v1.y, v1.y, fmaf(v1.z, v1.z, fmaf(v1.w, v1.w, s))));
    }
    #pragma unroll
    for (int o = 32; o; o >>= 1) s += __shfl_xor(s, o, 64);
    if (lane == 0) inv_norm[row] = 1.0f / sqrtf(fmaxf(s, 1e-12f));
}

// ---------------- kernel 2: split-bf16 MFMA scores + block argmax ----------------
__global__ __launch_bounds__(256) void score_argmax(const void* __restrict__ ctxv,
                                                    const void* __restrict__ memv,
                                                    const uint32_t* __restrict__ flag,
                                                    const float* __restrict__ inv_norm,
                                                    unsigned long long* __restrict__ g_best) {
    __shared__ __align__(16) uint16_t a_hi[BM][LDSPAD];
    __shared__ __align__(16) uint16_t a_lo[BM][LDSPAD];
    __shared__ __align__(16) uint16_t b_hi[BB][LDSPAD];
    __shared__ __align__(16) uint16_t b_lo[BB][LDSPAD];
    __shared__ unsigned long long s_best[BB];

    const int t    = threadIdx.x;
    const int b0   = blockIdx.x * BB;
    const int m0   = blockIdx.y * BM;
    const int lane = t & 63;
    const int w    = t >> 6;
    const int wm   = w >> 1;
    const int wb   = w & 1;
    const int quad = lane >> 4;
    const int l15  = lane & 15;
    const int srow = t >> 2;
    const int scol = (t & 3) * 8;

    if (t < BB) s_best[t] = 0ull;

    floatx4 acc[4][4];
    #pragma unroll
    for (int i = 0; i < 4; ++i)
        #pragma unroll
        for (int j = 0; j < 4; ++j)
            acc[i][j] = (floatx4){0.f, 0.f, 0.f, 0.f};

    const bool isbf = (*flag != 0u);   // wave-uniform

    for (int k0 = 0; k0 < D_DIM; k0 += BK) {
        __syncthreads();
        #pragma unroll
        for (int p = 0; p < 2; ++p) {
            const int r = srow + 64 * p;
            if (isbf) {
                // exact bf16 inputs: lo == 0, hi = input (lo tiles unused)
                const uint4* pa = (const uint4*)((const uint16_t*)memv + (size_t)(m0 + r) * D_DIM + k0 + scol);
                *(uint4*)&a_hi[r][scol] = *pa;
                const uint4* pb = (const uint4*)((const uint16_t*)ctxv + (size_t)(b0 + r) * D_DIM + k0 + scol);
                *(uint4*)&b_hi[r][scol] = *pb;
            } else {
                const float4* pa = (const float4*)((const float*)memv + (size_t)(m0 + r) * D_DIM + k0 + scol);
                float4 a0 = pa[0], a1 = pa[1];
                float av[8] = {a0.x, a0.y, a0.z, a0.w, a1.x, a1.y, a1.z, a1.w};
                uint16_t h[8], l[8];
                #pragma unroll
                for (int e = 0; e < 8; ++e) split_bf16(av[e], h[e], l[e]);
                #pragma unroll
                for (int e = 0; e < 8; ++e) { a_hi[r][scol + e] = h[e]; a_lo[r][scol + e] = l[e]; }

                const float4* pb = (const float4*)((const float*)ctxv + (size_t)(b0 + r) * D_DIM + k0 + scol);
                float4 c0 = pb[0], c1 = pb[1];
                float bv[8] = {c0.x, c0.y, c0.z, c0.w, c1.x, c1.y, c1.z, c1.w};
                #pragma unroll
                for (int e = 0; e < 8; ++e) split_bf16(bv[e], h[e], l[e]);
                #pragma unroll
                for (int e = 0; e < 8; ++e) { b_hi[r][scol + e] = h[e]; b_lo[r][scol + e] = l[e]; }
            }
        }
        __syncthreads();

        short8 ah[4], al[4];
        #pragma unroll
        for (int i = 0; i < 4; ++i)
            ah[i] = *(const short8*)&a_hi[wm * 64 + i * 16 + l15][quad * 8];
        if (!isbf) {
            #pragma unroll
            for (int i = 0; i < 4; ++i)
                al[i] = *(const short8*)&a_lo[wm * 64 + i * 16 + l15][quad * 8];
        }

        #pragma unroll
        for (int j = 0; j < 4; ++j) {
            short8 bh = *(const short8*)&b_hi[wb * 64 + j * 16 + l15][quad * 8];
            #pragma unroll
            for (int i = 0; i < 4; ++i)
                acc[i][j] = __builtin_amdgcn_mfma_f32_16x16x32_bf16(ah[i], bh, acc[i][j], 0, 0, 0);
            if (!isbf) {
                short8 bl = *(const short8*)&b_lo[wb * 64 + j * 16 + l15][quad * 8];
                #pragma unroll
                for (int i = 0; i < 4; ++i) {
                    acc[i][j] = __builtin_amdgcn_mfma_f32_16x16x32_bf16(ah[i], bl, acc[i][j], 0, 0, 0);
                    acc[i][j] = __builtin_amdgcn_mfma_f32_16x16x32_bf16(al[i], bh, acc[i][j], 0, 0, 0);
                }
            }
        }
    }

    // ---- epilogue: scale by mem inv_norm, packed-key argmax ----
    // C/D layout (m89): col(ctx) = lane&15, row(mem) = quad*4 + reg
    float rn[4][4];
    #pragma unroll
    for (int i = 0; i < 4; ++i)
        #pragma unroll
        for (int r = 0; r < 4; ++r)
            rn[i][r] = inv_norm[m0 + wm * 64 + i * 16 + quad * 4 + r];

    #pragma unroll
    for (int j = 0; j < 4; ++j) {
        unsigned long long best = 0ull;
        #pragma unroll
        for (int i = 0; i < 4; ++i)
            #pragma unroll
            for (int r = 0; r < 4; ++r) {
                float sc = acc[i][j][r] * rn[i][r];
                uint32_t mg = (uint32_t)(m0 + wm * 64 + i * 16 + quad * 4 + r);
                unsigned long long key =
                    ((unsigned long long)f32_order(sc) << 32) | (uint32_t)(~mg);
                best = best > key ? best : key;
            }
        atomicMax(&s_best[wb * 64 + j * 16 + l15], best);
    }
    __syncthreads();
    if (t < BB) atomicMax(&g_best[b0 + t], s_best[t]);
}

// ---------------- kernel 3: gather best rows ----------------
__global__ void gather_out(const void* __restrict__ memv,
                           const uint32_t* __restrict__ flag,
                           const unsigned long long* __restrict__ g_best,
                           void* __restrict__ outv) {
    const int b = blockIdx.x;
    const int t = threadIdx.x;   // 64
    const uint32_t m = ~(uint32_t)(g_best[b]);
    if (*flag) {
        const uint4* src = (const uint4*)((const uint16_t*)memv + (size_t)m * D_DIM);
        uint4* dst = (uint4*)((uint16_t*)outv + (size_t)b * D_DIM);
        dst[t] = src[t];
    } else {
        const float4* src = (const float4*)((const float*)memv + (size_t)m * D_DIM);
        float4* dst = (float4*)((float*)outv + (size_t)b * D_DIM);
        dst[t] = src[t];
        dst[t + 64] = src[t + 64];
    }
}

extern "C" void kernel_launch(void* const* d_in, const int* in_sizes, int n_in,
                              void* d_out, int out_size, void* d_ws, size_t ws_size,
                              hipStream_t stream) {
    const void* ctx = d_in[0];
    const void* mem = d_in[1];
    if (in_sizes[0] > in_sizes[1]) { ctx = d_in[1]; mem = d_in[0]; }  // ctx is smaller

    unsigned long long* g_best = (unsigned long long*)d_ws;
    uint32_t* flag = (uint32_t*)((char*)d_ws + 4096);
    float* inv_norm = (float*)((char*)d_ws + 8192);

    detect_init<<<1, 64, 0, stream>>>((const uint32_t*)mem, g_best, flag);
    norm_kernel<<<M_MEM / 4, 256, 0, stream>>>(mem, flag, inv_norm);
    dim3 grid(B_CTX / BB, M_MEM / BM);
    score_argmax<<<grid, 256, 0, stream>>>(ctx, mem, flag, inv_norm, g_best);
    gather_out<<<B_CTX, 64, 0, stream>>>(mem, flag, g_best, d_out);
}